// Round 4
// baseline (248.421 us; speedup 1.0000x reference)
//
#include <hip/hip_runtime.h>

// DropNorm: B=4096 rows, F=8192 features, fp32.
//   n = F/2; mu = sum(x*m)/n; sigma2 = sum(((x-mu)*m)^2)/(n-1)
//   out = gamma*m*(x-mu)*rsqrt(sigma2^2 + 1e-4) + beta   [sigma2 SQUARED: quirk]
//
// R4: raise in-flight bytes per CU. R1-R3 all pinned at ~2.5 TB/s because a
// wave only ever has ~256 B of loads in flight before draining at a waitcnt
// (Little's law: 20 waves x 256 B / ~375 ns = ~3 TB/s ceiling). Fix: DMA the
// whole 32 KB row to LDS with global_load_lds_dwordx4 (1 KB in flight per
// instruction, no VGPRs): 32 KB in flight per block, ~128 KB per CU.

constexpr int Bn = 4096;
constexpr int Fn = 8192;
constexpr int NT = 256;           // threads per block = 4 waves
constexpr int PT = Fn / (NT * 4); // 8 float4 per thread

typedef float f4 __attribute__((ext_vector_type(4)));
typedef const __attribute__((address_space(1))) unsigned int* gp_t; // global
typedef __attribute__((address_space(3))) unsigned int* lp_t;       // LDS

#define EPSV 1e-4f

// Prep: detect mask storage layout (uint8 bool vs int32) and materialize
//   m01[j] = mask ? 1.0 : 0.0 ;  mg[j] = mask ? gamma[j] : 0.0
// Detection: count nonzero among the first Fn BYTES. uint8 layout -> exactly
// Fn/2 = 4096; int32 layout -> those bytes span only 2048 ints -> count <= 2048.
__global__ __launch_bounds__(NT) void prep_kernel(const void* __restrict__ mask_raw,
                                                  const float* __restrict__ gamma,
                                                  float* __restrict__ m01,
                                                  float* __restrict__ mg) {
    const unsigned char* mb = (const unsigned char*)mask_raw;
    const int* mi = (const int*)mask_raw;
    const int tid = threadIdx.x;

    int cnt = 0;
    for (int j = tid; j < Fn; j += NT) cnt += (mb[j] != 0) ? 1 : 0;
    for (int off = 32; off > 0; off >>= 1) cnt += __shfl_down(cnt, off, 64);

    __shared__ int wc[NT / 64];
    __shared__ int flag;
    if ((tid & 63) == 0) wc[tid >> 6] = cnt;
    __syncthreads();
    if (tid == 0) {
        int total = wc[0] + wc[1] + wc[2] + wc[3];
        flag = (total == Fn / 2) ? 1 : 0;   // 1 = uint8 layout, 0 = int32 layout
    }
    __syncthreads();
    const bool u8 = (flag != 0);

    const int per_block = Fn / gridDim.x;
    const int base = blockIdx.x * per_block;
    for (int j = base + tid; j < base + per_block; j += NT) {
        const bool on = u8 ? (mb[j] != 0) : (mi[j] != 0);
        m01[j] = on ? 1.0f : 0.0f;
        mg[j]  = on ? gamma[j] : 0.0f;
    }
}

__global__ __launch_bounds__(NT, 4) void dropnorm_kernel(const float* __restrict__ x,
                                                         const float* __restrict__ m01,
                                                         const float* __restrict__ mg,
                                                         const float* __restrict__ beta,
                                                         float* __restrict__ out) {
    __shared__ f4 srow[Fn / 4];            // 32 KB: the staged row (dense, no pad —
                                           // global_load_lds needs base + lane*16)
    __shared__ float rs[NT / 64], rss[NT / 64];

    const int row  = blockIdx.x;
    const int tid  = threadIdx.x;
    const int wave = tid >> 6;
    const int lane = tid & 63;

    // ---- DMA the whole row to LDS: wave w, instr i covers bytes
    //      [w*8192 + i*1024 + lane*16, +16). Identity global<->LDS mapping.
    {
        const char* gb = (const char*)(x + (size_t)row * Fn) + wave * 8192 + lane * 16;
        char* lb = (char*)srow + wave * 8192;   // wave-uniform LDS base
#pragma unroll
        for (int i = 0; i < 8; ++i)
            __builtin_amdgcn_global_load_lds((gp_t)(gb + i * 1024),
                                             (lp_t)(lb + i * 1024), 16, 0, 0);
    }

    // ---- broadcast mask loads into registers (overlap the DMA; L2-hot)
    const f4* __restrict__ m4 = (const f4*)m01;
    f4 mv[PT];
#pragma unroll
    for (int k = 0; k < PT; ++k) mv[k] = m4[tid + k * NT];

    __syncthreads();   // drains DMA; row now in LDS

    // ---- stats from LDS
    float s = 0.f, ss = 0.f;
#pragma unroll
    for (int k = 0; k < PT; ++k) {
        const f4 xv = srow[tid + k * NT];    // dense ds_read_b128, conflict-free
        const float a0 = xv.x * mv[k].x;
        const float a1 = xv.y * mv[k].y;
        const float a2 = xv.z * mv[k].z;
        const float a3 = xv.w * mv[k].w;
        s  += (a0 + a1) + (a2 + a3);
        ss += (a0 * a0 + a1 * a1) + (a2 * a2 + a3 * a3);
    }
    for (int off = 32; off > 0; off >>= 1) {
        s  += __shfl_down(s, off, 64);
        ss += __shfl_down(ss, off, 64);
    }
    if (lane == 0) { rs[wave] = s; rss[wave] = ss; }

    // ---- issue epilogue broadcast loads BEFORE the barrier so they overlap it
    const f4* __restrict__ mg4 = (const f4*)mg;
    const f4* __restrict__ b4  = (const f4*)beta;
    f4 gv[PT], bv[PT];
#pragma unroll
    for (int k = 0; k < PT; ++k) gv[k] = mg4[tid + k * NT];
#pragma unroll
    for (int k = 0; k < PT; ++k) bv[k] = b4[tid + k * NT];

    __syncthreads();
    const float S  = (rs[0] + rs[1]) + (rs[2] + rs[3]);
    const float SS = (rss[0] + rss[1]) + (rss[2] + rss[3]);

    const float n  = (float)(Fn / 2);
    const float mu = S / n;
    // sum(diff^2) = sum(x^2 m) - n*mu^2   (sum(m) == n exactly)
    const float sigma2 = (SS - n * mu * mu) / (n - 1.0f);
    const float inv = rsqrtf(sigma2 * sigma2 + EPSV);  // quirk: sigma2 squared

    // ---- epilogue: compute from LDS row, stream out (never re-read -> NT store)
    f4* __restrict__ o4 = (f4*)(out + (size_t)row * Fn);
#pragma unroll
    for (int k = 0; k < PT; ++k) {
        const int idx = tid + k * NT;
        const f4 xv = srow[idx];
        f4 o;
        o.x = gv[k].x * (xv.x - mu) * inv + bv[k].x;
        o.y = gv[k].y * (xv.y - mu) * inv + bv[k].y;
        o.z = gv[k].z * (xv.z - mu) * inv + bv[k].z;
        o.w = gv[k].w * (xv.w - mu) * inv + bv[k].w;
        __builtin_nontemporal_store(o, o4 + idx);
    }
}

extern "C" void kernel_launch(void* const* d_in, const int* in_sizes, int n_in,
                              void* d_out, int out_size, void* d_ws, size_t ws_size,
                              hipStream_t stream) {
    const float* x     = (const float*)d_in[0];
    const float* gamma = (const float*)d_in[1];
    const float* beta  = (const float*)d_in[2];
    const void*  mask  = d_in[3];
    float* out = (float*)d_out;

    float* m01 = (float*)d_ws;       // Fn floats
    float* mg  = m01 + Fn;           // Fn floats

    prep_kernel<<<16, NT, 0, stream>>>(mask, gamma, m01, mg);
    dropnorm_kernel<<<Bn, NT, 0, stream>>>(x, m01, mg, beta, out);
}